// Round 15
// baseline (447.334 us; speedup 1.0000x reference)
//
#include <hip/hip_runtime.h>
#include <hip/hip_bf16.h>

// Problem constants
#define HH 256
#define WW 256
#define CCH 1024
#define PP 1024     // 32*32 patches per image
#define SROWS 64    // image rows per stripe
#define SPATCH 256  // patches per stripe (8 patch-rows * 32)

using f32x4 = __attribute__((ext_vector_type(4))) float;
using short8 = __attribute__((ext_vector_type(8))) short;

// ---------------------------------------------------------------------------
// pool_direct (R10-proven): job = ph*32 + cc -> patches (ph, 0..31) of planes
// cc*32..cc*32+31.  PLAIN f32x4 loads (x must allocate in L3 for apply's
// re-read).  Writeback short8 (16B), 64B cross-block granularity.
// ---------------------------------------------------------------------------
__device__ __forceinline__ void pool_body(const float* __restrict__ xb,
                                          __hip_bfloat16* __restrict__ yTb,
                                          int job, int t) {
    __shared__ float lds[32][33];
    int ph = job >> 5, c0 = (job & 31) * 32;
    int wid = t >> 6, lane = t & 63;
#pragma unroll 2
    for (int i = 0; i < 8; ++i) {
        int cl = wid * 8 + i;
        const float* base = xb + (size_t)(c0 + cl) * (HH * WW)
                          + (size_t)ph * 8 * WW + lane * 4;
        float acc = 0.f;
#pragma unroll
        for (int r = 0; r < 8; ++r) {
            f32x4 v = *(const f32x4*)(base + r * WW);
            acc += v.x + v.y + v.z + v.w;
        }
        acc += __shfl_xor(acc, 1);
        if ((lane & 1) == 0)
            lds[lane >> 1][cl] = acc * (1.f / 64.f);
    }
    __syncthreads();
    if (t < 128) {
        int row = t >> 2, q = t & 3;
        short8 s;
#pragma unroll
        for (int j = 0; j < 8; ++j) {
            __hip_bfloat16 h = __float2bfloat16(lds[row][q * 8 + j]);
            s[j] = (short)reinterpret_cast<unsigned short&>(h);
        }
        *(short8*)(yTb + (size_t)(1 + ph * 32 + row) * CCH + c0 + q * 8) = s;
    }
}

// ---------------------------------------------------------------------------
// gemm stripe body: gate[:, p in stripe s] for 256 patches.  job 0..127:
// co_tile = job&15 (64 co), ptile = job>>4 (32 p).  Wave tile 16x32 (R10).
// Requires yT rows [s*256 .. s*256+257] valid (pool(s), pool(s+1) or pad).
// ---------------------------------------------------------------------------
__device__ __forceinline__ void gemm_body(const __hip_bfloat16* __restrict__ wT,
                                          const __hip_bfloat16* __restrict__ yTb,
                                          float* __restrict__ gateb,
                                          int s, int job, int tid) {
    int lane = tid & 63;
    int wid  = tid >> 6;
    int l15 = lane & 15, lhi = lane >> 4;
    int co_base = (job & 15) * 64 + wid * 16;
    int p_base  = s * SPATCH + (job >> 4) * 32;
    f32x4 acc[2] = {};
#pragma unroll
    for (int tap = 0; tap < 3; ++tap) {
        const __hip_bfloat16* Ap = wT + (size_t)tap * (1u << 20)
                                 + (size_t)(co_base + l15) * CCH + lhi * 8;
        const __hip_bfloat16* Bp = yTb + (size_t)(p_base + l15 + tap) * CCH + lhi * 8;
        for (int ci0 = 0; ci0 < CCH; ci0 += 32) {
            short8 a0 = *(const short8*)(Ap + ci0);
            short8 b0 = *(const short8*)(Bp + ci0);
            short8 b1 = *(const short8*)(Bp + ci0 + 16 * CCH);
            acc[0] = __builtin_amdgcn_mfma_f32_16x16x32_bf16(a0, b0, acc[0], 0, 0, 0);
            acc[1] = __builtin_amdgcn_mfma_f32_16x16x32_bf16(a0, b1, acc[1], 0, 0, 0);
        }
    }
    // C/D layout: col = lane&15, row = (lane>>4)*4 + reg  [m89/m91].
#pragma unroll
    for (int j16 = 0; j16 < 2; ++j16) {
        int col  = p_base + j16 * 16 + l15;
        int row0 = co_base + lhi * 4;
#pragma unroll
        for (int r = 0; r < 4; ++r)
            gateb[(size_t)(row0 + r) * PP + col] = 1.f / (1.f + __expf(-acc[j16][r]));
    }
}

// ---------------------------------------------------------------------------
// apply stripe body: plane x stripe (64 rows).  Gate slice (256 f32, 1KB) in
// LDS; PLAIN x loads (L3 hits from pool's allocation); NT out stores.
// ---------------------------------------------------------------------------
__device__ __forceinline__ void apply_body(const float* __restrict__ xb,
                                           const float* __restrict__ gateb,
                                           float* __restrict__ outb,
                                           int s, int plane, int t) {
    __shared__ __align__(16) float g[SPATCH];
    const float* xp = xb   + (size_t)plane * (HH * WW) + (size_t)s * SROWS * WW;
    float*       op = outb + (size_t)plane * (HH * WW) + (size_t)s * SROWS * WW;
    if (t < 64)
        ((f32x4*)g)[t] = ((const f32x4*)(gateb + (size_t)plane * PP + s * SPATCH))[t];
    __syncthreads();
    int col4 = t & 63;
    int r    = t >> 6;
    int pc   = col4 >> 1;
#pragma unroll 4
    for (int it = 0; it < 16; ++it) {
        int row = it * 4 + r;                    // 0..63 within stripe
        float gg = g[(row >> 3) * 32 + pc];
        size_t off = (size_t)row * 64 + col4;    // f32x4 units
        f32x4 v = *((const f32x4*)xp + off);
        v *= gg;
        __builtin_nontemporal_store(v, (f32x4*)op + off);
    }
}

// ---------------------------------------------------------------------------
// Phase A: wconv+pad [0,256) ∥ pool(b0,s0) [256,512) ∥ pool(b0,s1) [512,768).
// ---------------------------------------------------------------------------
__global__ __launch_bounds__(256) void phaseA_kernel(
        const float* __restrict__ x, const float* __restrict__ w,
        __hip_bfloat16* __restrict__ yT, __hip_bfloat16* __restrict__ wT) {
    int bid = blockIdx.x, t = threadIdx.x;
    if (bid < 256) {
        int base = bid * 256 + t;                // 0..65535
#pragma unroll
        for (int it = 0; it < 16; ++it) {
            int idx = it * (1 << 16) + base;     // co*1024+ci
            const float* p = w + (size_t)idx * 3;
            wT[idx]               = __float2bfloat16(p[0]);
            wT[(1u << 20) + idx]  = __float2bfloat16(p[1]);
            wT[(2u << 20) + idx]  = __float2bfloat16(p[2]);
        }
        if (base < 2 * CCH) {
            int bb = base >> 10, cc = base & 1023;
            __hip_bfloat16 z = __float2bfloat16(0.f);
            __hip_bfloat16* basep = yT + (size_t)bb * (PP + 2) * CCH;
            basep[cc] = z;
            basep[(size_t)(PP + 1) * CCH + cc] = z;
        }
    } else {
        int s = (bid - 256) >> 8;                // 0 or 1
        int job = (bid - 256) & 255;
        pool_body(x, yT, s * SPATCH + job, t);
    }
}

// ---------------------------------------------------------------------------
// Generic phase: [gemm 128] ∥ [pool 256] ∥ [apply 1024], each optional
// (batch index < 0 => absent).  Block ranges in that order.
// ---------------------------------------------------------------------------
__global__ __launch_bounds__(256) void phase_kernel(
        const float* __restrict__ x, float* __restrict__ out,
        __hip_bfloat16* __restrict__ yT, __hip_bfloat16* __restrict__ wT,
        float* __restrict__ gate,
        int gB, int gS, int pB, int pS, int aB, int aS) {
    int bid = blockIdx.x, t = threadIdx.x;
    int nG = (gB >= 0) ? 128 : 0;
    int nP = (pB >= 0) ? 256 : 0;
    if (bid < nG) {
        const __hip_bfloat16* yTb = yT + (size_t)gB * (PP + 2) * CCH;
        float* gateb = gate + (size_t)gB * CCH * PP;
        gemm_body(wT, yTb, gateb, gS, bid, t);
        return;
    }
    bid -= nG;
    if (bid < nP) {
        const float* xb = x + (size_t)pB * CCH * HH * WW;
        __hip_bfloat16* yTb = yT + (size_t)pB * (PP + 2) * CCH;
        pool_body(xb, yTb, pS * SPATCH + bid, t);
        return;
    }
    bid -= nP;
    {
        const float* xb = x + (size_t)aB * CCH * HH * WW;
        const float* gateb = gate + (size_t)aB * CCH * PP;
        float* outb = out + (size_t)aB * CCH * HH * WW;
        apply_body(xb, gateb, outb, aS, bid, t);
    }
}

extern "C" void kernel_launch(void* const* d_in, const int* in_sizes, int n_in,
                              void* d_out, int out_size, void* d_ws, size_t ws_size,
                              hipStream_t stream) {
    const float* x = (const float*)d_in[0];       // [2,1024,256,256] f32
    const float* w = (const float*)d_in[1];       // [1024,1024,3] f32
    float* out = (float*)d_out;                   // [2,1024,256,256] f32

    // Workspace layout (256-aligned):
    //   yT   bf16 [2][1026][1024]   4,202,496 B @ 0
    //   wT   bf16 [3][1024][1024]   6,291,456 B @  4,202,496
    //   gate f32  [2][1024][1024]   8,388,608 B @ 10,493,952   (tot ~18.9 MiB)
    char* ws = (char*)d_ws;
    __hip_bfloat16* yT   = (__hip_bfloat16*)(ws);
    __hip_bfloat16* wT   = (__hip_bfloat16*)(ws + 4202496);
    float*          gate = (float*)(ws + 10493952);

    // Stripe pipeline: pool(s) -> [after pool(s+1)] gemm(s) -> apply(s).
    // apply(s) re-reads its x stripe ~2 phases after pool(s) -> L3-resident.
    struct Ph { int gB, gS, pB, pS, aB, aS; };
    const Ph phases[] = {
        { 0, 0,  0, 2, -1, -1},   // B: gemm(0,0) | pool(0,2)
        { 0, 1,  0, 3,  0,  0},   // C: gemm(0,1) | pool(0,3) | apply(0,0)
        { 0, 2,  1, 0,  0,  1},   // D
        { 0, 3,  1, 1,  0,  2},   // E
        { 1, 0,  1, 2,  0,  3},   // F
        { 1, 1,  1, 3,  1,  0},   // G
        { 1, 2, -1, -1, 1,  1},   // H
        { 1, 3, -1, -1, 1,  2},   // I
        {-1, -1, -1, -1, 1, 3},   // J
    };

    hipLaunchKernelGGL(phaseA_kernel, dim3(768), dim3(256), 0, stream, x, w, yT, wT);
    for (const Ph& p : phases) {
        int grid = (p.gB >= 0 ? 128 : 0) + (p.pB >= 0 ? 256 : 0)
                 + (p.aB >= 0 ? 1024 : 0);
        hipLaunchKernelGGL(phase_kernel, dim3(grid), dim3(256), 0, stream,
                           x, out, yT, wT, gate,
                           p.gB, p.gS, p.pB, p.pS, p.aB, p.aS);
    }
}

// Round 16
// 441.763 us; speedup vs baseline: 1.0126x; 1.0126x over previous
//
#include <hip/hip_runtime.h>
#include <hip/hip_bf16.h>

// Problem constants
#define HH 256
#define WW 256
#define CCH 1024
#define PP 1024   // 32*32 patches per image

using f32x4 = __attribute__((ext_vector_type(4))) float;
using short8 = __attribute__((ext_vector_type(8))) short;

// ---------------------------------------------------------------------------
// pool_direct (R10-proven, byte-identical): job = ph*32 + cc -> patches
// (ph, 0..31) of planes cc*32..cc*32+31.  NT f32x4 slab reads, shfl_xor(1)
// pair-reduce -> LDS; writeback short8 (16B), 64B cross-block granularity.
// ---------------------------------------------------------------------------
__device__ __forceinline__ void pool_direct_body(const float* __restrict__ xb,
                                                 __hip_bfloat16* __restrict__ yTb,
                                                 int job, int t) {
    __shared__ float lds[32][33];
    int ph = job >> 5, c0 = (job & 31) * 32;
    int wid = t >> 6, lane = t & 63;
#pragma unroll 2
    for (int i = 0; i < 8; ++i) {
        int cl = wid * 8 + i;
        const float* base = xb + (size_t)(c0 + cl) * (HH * WW)
                          + (size_t)ph * 8 * WW + lane * 4;
        float acc = 0.f;
#pragma unroll
        for (int r = 0; r < 8; ++r) {
            f32x4 v = __builtin_nontemporal_load((const f32x4*)(base + r * WW));
            acc += v.x + v.y + v.z + v.w;
        }
        acc += __shfl_xor(acc, 1);
        if ((lane & 1) == 0)
            lds[lane >> 1][cl] = acc * (1.f / 64.f);
    }
    __syncthreads();
    if (t < 128) {
        int row = t >> 2, q = t & 3;
        short8 s;
#pragma unroll
        for (int j = 0; j < 8; ++j) {
            __hip_bfloat16 h = __float2bfloat16(lds[row][q * 8 + j]);
            s[j] = (short)reinterpret_cast<unsigned short&>(h);
        }
        *(short8*)(yTb + (size_t)(1 + ph * 32 + row) * CCH + c0 + q * 8) = s;
    }
}

// ---------------------------------------------------------------------------
// gemm body (R10-proven, byte-identical): block = 64(co) x 32(p), 4 waves
// along co, wave tile 16x32.  job in 0..511.
// ---------------------------------------------------------------------------
__device__ __forceinline__ void gemm_body(const __hip_bfloat16* __restrict__ wT,
                                          const __hip_bfloat16* __restrict__ yTb,
                                          float* __restrict__ gateb,
                                          int job, int tid) {
    int lane = tid & 63;
    int wid  = tid >> 6;
    int l15 = lane & 15, lhi = lane >> 4;
    int co_base = (job & 15) * 64 + wid * 16;
    int p_base  = (job >> 4) * 32;
    f32x4 acc[2] = {};
#pragma unroll
    for (int tap = 0; tap < 3; ++tap) {
        const __hip_bfloat16* Ap = wT + (size_t)tap * (1u << 20)
                                 + (size_t)(co_base + l15) * CCH + lhi * 8;
        const __hip_bfloat16* Bp = yTb + (size_t)(p_base + l15 + tap) * CCH + lhi * 8;
        for (int ci0 = 0; ci0 < CCH; ci0 += 32) {
            short8 a0 = *(const short8*)(Ap + ci0);
            short8 b0 = *(const short8*)(Bp + ci0);
            short8 b1 = *(const short8*)(Bp + ci0 + 16 * CCH);
            acc[0] = __builtin_amdgcn_mfma_f32_16x16x32_bf16(a0, b0, acc[0], 0, 0, 0);
            acc[1] = __builtin_amdgcn_mfma_f32_16x16x32_bf16(a0, b1, acc[1], 0, 0, 0);
        }
    }
    // C/D layout: col = lane&15, row = (lane>>4)*4 + reg  [m89/m91].
#pragma unroll
    for (int j16 = 0; j16 < 2; ++j16) {
        int col  = p_base + j16 * 16 + l15;
        int row0 = co_base + lhi * 4;
#pragma unroll
        for (int r = 0; r < 4; ++r)
            gateb[(size_t)(row0 + r) * PP + col] = 1.f / (1.f + __expf(-acc[j16][r]));
    }
}

// ---------------------------------------------------------------------------
// apply FLAT (R16's single change): dense-window grid-stride sweep.  1024
// blocks x 256 threads cover one batch; per iteration the WHOLE grid touches
// one contiguous 4 MB window (fill/copy-ubench access pattern), sweeping
// backward so the tail of x (L3-warm from pool) is re-read first.  Gate is a
// scalar L1/L2 load via index math; no LDS, no barrier.  NT load + NT store.
// ---------------------------------------------------------------------------
__device__ __forceinline__ void apply_flat_body(const float* __restrict__ xb,
                                                const float* __restrict__ gateb,
                                                float* __restrict__ outb,
                                                int bid, int t) {
    const f32x4* x4 = (const f32x4*)xb;
    f32x4*       o4 = (f32x4*)outb;
    int tid = bid * 256 + t;                    // 0..262143
#pragma unroll 4
    for (int it = 63; it >= 0; --it) {
        size_t i4 = ((size_t)it << 18) + tid;   // f32x4 index in batch (2^24)
        int c   = (int)(i4 >> 14);              // plane (16384 f32x4/plane)
        int j   = (int)(i4 & 16383);
        int row = j >> 6, col4 = j & 63;
        int p   = ((row >> 3) << 5) + (col4 >> 1);
        float gg = gateb[(size_t)c * PP + p];
        f32x4 v = __builtin_nontemporal_load(x4 + i4);
        v *= gg;
        __builtin_nontemporal_store(v, o4 + i4);
    }
}

// ---------------------------------------------------------------------------
// L1: pool_direct(b0) [blocks 0..1023] ∥ wconv+pad [blocks 1024..1279].
// ---------------------------------------------------------------------------
__global__ __launch_bounds__(256) void pool0_wconv_kernel(
        const float* __restrict__ x, const float* __restrict__ w,
        __hip_bfloat16* __restrict__ yT, __hip_bfloat16* __restrict__ wT) {
    int bid = blockIdx.x, t = threadIdx.x;
    if (bid < 1024) {
        pool_direct_body(x, yT, bid, t);
    } else {
        int base = (bid - 1024) * 256 + t;       // 0..65535
#pragma unroll
        for (int it = 0; it < 16; ++it) {
            int idx = it * (1 << 16) + base;     // co*1024+ci
            const float* p = w + (size_t)idx * 3;
            wT[idx]               = __float2bfloat16(p[0]);
            wT[(1u << 20) + idx]  = __float2bfloat16(p[1]);
            wT[(2u << 20) + idx]  = __float2bfloat16(p[2]);
        }
        if (base < 2 * CCH) {
            int bb = base >> 10, cc = base & 1023;
            __hip_bfloat16 z = __float2bfloat16(0.f);
            __hip_bfloat16* basep = yT + (size_t)bb * (PP + 2) * CCH;
            basep[cc] = z;
            basep[(size_t)(PP + 1) * CCH + cc] = z;
        }
    }
}

// ---------------------------------------------------------------------------
// L2: gemm0 [blocks 0..511] ∥ pool_direct(b1) [512..1535].
// ---------------------------------------------------------------------------
__global__ __launch_bounds__(256) void gemm0_pool1_kernel(
        const float* __restrict__ x, const __hip_bfloat16* __restrict__ wT,
        __hip_bfloat16* __restrict__ yT, float* __restrict__ gate) {
    int bid = blockIdx.x, t = threadIdx.x;
    if (bid < 512) {
        gemm_body(wT, yT, gate, bid, t);
    } else {
        const float* x1 = x + (size_t)CCH * HH * WW;
        __hip_bfloat16* yT1 = yT + (size_t)(PP + 2) * CCH;
        pool_direct_body(x1, yT1, bid - 512, t);
    }
}

// ---------------------------------------------------------------------------
// L3: gemm1 [blocks 0..511] ∥ apply0-flat [512..1535].
// ---------------------------------------------------------------------------
__global__ __launch_bounds__(256) void gemm1_apply0_kernel(
        const float* __restrict__ x, const __hip_bfloat16* __restrict__ wT,
        const __hip_bfloat16* __restrict__ yT, float* __restrict__ gate,
        float* __restrict__ out) {
    int bid = blockIdx.x, t = threadIdx.x;
    if (bid < 512) {
        const __hip_bfloat16* yT1 = yT + (size_t)(PP + 2) * CCH;
        float* gate1 = gate + (size_t)CCH * PP;
        gemm_body(wT, yT1, gate1, bid, t);
    } else {
        apply_flat_body(x, gate, out, bid - 512, t);
    }
}

// ---------------------------------------------------------------------------
// L4: apply1-flat.
// ---------------------------------------------------------------------------
__global__ __launch_bounds__(256) void apply1_kernel(
        const float* __restrict__ x, const float* __restrict__ gate,
        float* __restrict__ out) {
    const float* x1    = x    + (size_t)CCH * HH * WW;
    const float* gate1 = gate + (size_t)CCH * PP;
    float*       out1  = out  + (size_t)CCH * HH * WW;
    apply_flat_body(x1, gate1, out1, blockIdx.x, threadIdx.x);
}

extern "C" void kernel_launch(void* const* d_in, const int* in_sizes, int n_in,
                              void* d_out, int out_size, void* d_ws, size_t ws_size,
                              hipStream_t stream) {
    const float* x = (const float*)d_in[0];       // [2,1024,256,256] f32
    const float* w = (const float*)d_in[1];       // [1024,1024,3] f32
    float* out = (float*)d_out;                   // [2,1024,256,256] f32

    // Workspace layout (256-aligned):
    //   yT   bf16 [2][1026][1024]   4,202,496 B @ 0
    //   wT   bf16 [3][1024][1024]   6,291,456 B @  4,202,496
    //   gate f32  [2][1024][1024]   8,388,608 B @ 10,493,952   (tot ~18.9 MiB)
    char* ws = (char*)d_ws;
    __hip_bfloat16* yT   = (__hip_bfloat16*)(ws);
    __hip_bfloat16* wT   = (__hip_bfloat16*)(ws + 4202496);
    float*          gate = (float*)(ws + 10493952);

    hipLaunchKernelGGL(pool0_wconv_kernel, dim3(1280), dim3(256), 0, stream,
                       x, w, yT, wT);
    hipLaunchKernelGGL(gemm0_pool1_kernel, dim3(1536), dim3(256), 0, stream,
                       x, wT, yT, gate);
    hipLaunchKernelGGL(gemm1_apply0_kernel, dim3(1536), dim3(256), 0, stream,
                       x, wT, yT, gate, out);
    hipLaunchKernelGGL(apply1_kernel, dim3(1024), dim3(256), 0, stream,
                       x, gate, out);
}

// Round 17
// 420.376 us; speedup vs baseline: 1.0641x; 1.0509x over previous
//
#include <hip/hip_runtime.h>
#include <hip/hip_bf16.h>

// Problem constants
#define HH 256
#define WW 256
#define CCH 1024
#define PP 1024   // 32*32 patches per image

using f32x4 = __attribute__((ext_vector_type(4))) float;
using short8 = __attribute__((ext_vector_type(8))) short;

// ---------------------------------------------------------------------------
// pool_direct (R10 structure): job = ph*32 + cc -> patches (ph, 0..31) of
// planes cc*32..cc*32+31.  PLAIN f32x4 slab reads (R17's change: allocate x
// in L2/L3 so apply's reversed re-read can hit), shfl_xor(1) pair-reduce ->
// LDS; writeback short8 (16B), 64B cross-block granularity (replay-safe).
// ---------------------------------------------------------------------------
__device__ __forceinline__ void pool_direct_body(const float* __restrict__ xb,
                                                 __hip_bfloat16* __restrict__ yTb,
                                                 int job, int t) {
    __shared__ float lds[32][33];
    int ph = job >> 5, c0 = (job & 31) * 32;
    int wid = t >> 6, lane = t & 63;
#pragma unroll 2
    for (int i = 0; i < 8; ++i) {
        int cl = wid * 8 + i;
        const float* base = xb + (size_t)(c0 + cl) * (HH * WW)
                          + (size_t)ph * 8 * WW + lane * 4;
        float acc = 0.f;
#pragma unroll
        for (int r = 0; r < 8; ++r) {
            f32x4 v = *(const f32x4*)(base + r * WW);   // plain (was NT in R10)
            acc += v.x + v.y + v.z + v.w;
        }
        acc += __shfl_xor(acc, 1);
        if ((lane & 1) == 0)
            lds[lane >> 1][cl] = acc * (1.f / 64.f);
    }
    __syncthreads();
    if (t < 128) {
        int row = t >> 2, q = t & 3;
        short8 s;
#pragma unroll
        for (int j = 0; j < 8; ++j) {
            __hip_bfloat16 h = __float2bfloat16(lds[row][q * 8 + j]);
            s[j] = (short)reinterpret_cast<unsigned short&>(h);
        }
        *(short8*)(yTb + (size_t)(1 + ph * 32 + row) * CCH + c0 + q * 8) = s;
    }
}

// ---------------------------------------------------------------------------
// gemm body (R10-proven, byte-identical): block = 64(co) x 32(p), 4 waves
// along co, wave tile 16x32.  job in 0..511.
// ---------------------------------------------------------------------------
__device__ __forceinline__ void gemm_body(const __hip_bfloat16* __restrict__ wT,
                                          const __hip_bfloat16* __restrict__ yTb,
                                          float* __restrict__ gateb,
                                          int job, int tid) {
    int lane = tid & 63;
    int wid  = tid >> 6;
    int l15 = lane & 15, lhi = lane >> 4;
    int co_base = (job & 15) * 64 + wid * 16;
    int p_base  = (job >> 4) * 32;
    f32x4 acc[2] = {};
#pragma unroll
    for (int tap = 0; tap < 3; ++tap) {
        const __hip_bfloat16* Ap = wT + (size_t)tap * (1u << 20)
                                 + (size_t)(co_base + l15) * CCH + lhi * 8;
        const __hip_bfloat16* Bp = yTb + (size_t)(p_base + l15 + tap) * CCH + lhi * 8;
        for (int ci0 = 0; ci0 < CCH; ci0 += 32) {
            short8 a0 = *(const short8*)(Ap + ci0);
            short8 b0 = *(const short8*)(Bp + ci0);
            short8 b1 = *(const short8*)(Bp + ci0 + 16 * CCH);
            acc[0] = __builtin_amdgcn_mfma_f32_16x16x32_bf16(a0, b0, acc[0], 0, 0, 0);
            acc[1] = __builtin_amdgcn_mfma_f32_16x16x32_bf16(a0, b1, acc[1], 0, 0, 0);
        }
    }
    // C/D layout: col = lane&15, row = (lane>>4)*4 + reg  [m89/m91].
#pragma unroll
    for (int j16 = 0; j16 < 2; ++j16) {
        int col  = p_base + j16 * 16 + l15;
        int row0 = co_base + lhi * 4;
#pragma unroll
        for (int r = 0; r < 4; ++r)
            gateb[(size_t)(row0 + r) * PP + col] = 1.f / (1.f + __expf(-acc[j16][r]));
    }
}

// ---------------------------------------------------------------------------
// apply body (R10 structure): gate row (4KB) in LDS; wave covers a full
// 256-col row per iter.  PLAIN x loads (R17's change: hit the lines pool
// allocated), NT stores on out (R13-proven).
// ---------------------------------------------------------------------------
__device__ __forceinline__ void apply_body(const float* __restrict__ xb,
                                           const float* __restrict__ gateb,
                                           float* __restrict__ outb,
                                           int c, int t) {
    __shared__ __align__(16) float g[PP];
    const float* xp = xb   + (size_t)c * (HH * WW);
    float*       op = outb + (size_t)c * (HH * WW);
    ((f32x4*)g)[t] = ((const f32x4*)(gateb + (size_t)c * PP))[t];
    __syncthreads();
    int col4 = t & 63;
    int r    = t >> 6;
    int pc   = col4 >> 1;
#pragma unroll 4
    for (int it = 0; it < 64; ++it) {
        int row = it * 4 + r;
        float gg = g[(row >> 3) * 32 + pc];
        size_t off = (size_t)row * 64 + col4;
        f32x4 v = *((const f32x4*)xp + off);    // plain (was NT in R10)
        v *= gg;
        __builtin_nontemporal_store(v, (f32x4*)op + off);
    }
}

// ---------------------------------------------------------------------------
// L1: pool_direct(b0) [blocks 0..1023] ∥ wconv+pad [blocks 1024..1279].
// ---------------------------------------------------------------------------
__global__ __launch_bounds__(256) void pool0_wconv_kernel(
        const float* __restrict__ x, const float* __restrict__ w,
        __hip_bfloat16* __restrict__ yT, __hip_bfloat16* __restrict__ wT) {
    int bid = blockIdx.x, t = threadIdx.x;
    if (bid < 1024) {
        pool_direct_body(x, yT, bid, t);
    } else {
        int base = (bid - 1024) * 256 + t;       // 0..65535
#pragma unroll
        for (int it = 0; it < 16; ++it) {
            int idx = it * (1 << 16) + base;     // co*1024+ci
            const float* p = w + (size_t)idx * 3;
            wT[idx]               = __float2bfloat16(p[0]);
            wT[(1u << 20) + idx]  = __float2bfloat16(p[1]);
            wT[(2u << 20) + idx]  = __float2bfloat16(p[2]);
        }
        if (base < 2 * CCH) {
            int bb = base >> 10, cc = base & 1023;
            __hip_bfloat16 z = __float2bfloat16(0.f);
            __hip_bfloat16* basep = yT + (size_t)bb * (PP + 2) * CCH;
            basep[cc] = z;
            basep[(size_t)(PP + 1) * CCH + cc] = z;
        }
    }
}

// ---------------------------------------------------------------------------
// L2: gemm0 [blocks 0..511] ∥ pool_direct(b1) [512..1535].
// ---------------------------------------------------------------------------
__global__ __launch_bounds__(256) void gemm0_pool1_kernel(
        const float* __restrict__ x, const __hip_bfloat16* __restrict__ wT,
        __hip_bfloat16* __restrict__ yT, float* __restrict__ gate) {
    int bid = blockIdx.x, t = threadIdx.x;
    if (bid < 512) {
        gemm_body(wT, yT, gate, bid, t);
    } else {
        const float* x1 = x + (size_t)CCH * HH * WW;
        __hip_bfloat16* yT1 = yT + (size_t)(PP + 2) * CCH;
        pool_direct_body(x1, yT1, bid - 512, t);
    }
}

// ---------------------------------------------------------------------------
// L3: gemm1 [blocks 0..511] ∥ apply0 [512..1535, reversed planes so the
// planes pool0 read last (cache-resident) are re-read first].
// ---------------------------------------------------------------------------
__global__ __launch_bounds__(256) void gemm1_apply0_kernel(
        const float* __restrict__ x, const __hip_bfloat16* __restrict__ wT,
        const __hip_bfloat16* __restrict__ yT, float* __restrict__ gate,
        float* __restrict__ out) {
    int bid = blockIdx.x, t = threadIdx.x;
    if (bid < 512) {
        const __hip_bfloat16* yT1 = yT + (size_t)(PP + 2) * CCH;
        float* gate1 = gate + (size_t)CCH * PP;
        gemm_body(wT, yT1, gate1, bid, t);
    } else {
        apply_body(x, gate, out, 1023 - (bid - 512), t);
    }
}

// ---------------------------------------------------------------------------
// L4: apply1 (reversed planes).
// ---------------------------------------------------------------------------
__global__ __launch_bounds__(256) void apply1_kernel(
        const float* __restrict__ x, const float* __restrict__ gate,
        float* __restrict__ out) {
    const float* x1    = x    + (size_t)CCH * HH * WW;
    const float* gate1 = gate + (size_t)CCH * PP;
    float*       out1  = out  + (size_t)CCH * HH * WW;
    apply_body(x1, gate1, out1, 1023 - blockIdx.x, threadIdx.x);
}

extern "C" void kernel_launch(void* const* d_in, const int* in_sizes, int n_in,
                              void* d_out, int out_size, void* d_ws, size_t ws_size,
                              hipStream_t stream) {
    const float* x = (const float*)d_in[0];       // [2,1024,256,256] f32
    const float* w = (const float*)d_in[1];       // [1024,1024,3] f32
    float* out = (float*)d_out;                   // [2,1024,256,256] f32

    // Workspace layout (256-aligned):
    //   yT   bf16 [2][1026][1024]   4,202,496 B @ 0
    //   wT   bf16 [3][1024][1024]   6,291,456 B @  4,202,496
    //   gate f32  [2][1024][1024]   8,388,608 B @ 10,493,952   (tot ~18.9 MiB)
    char* ws = (char*)d_ws;
    __hip_bfloat16* yT   = (__hip_bfloat16*)(ws);
    __hip_bfloat16* wT   = (__hip_bfloat16*)(ws + 4202496);
    float*          gate = (float*)(ws + 10493952);

    hipLaunchKernelGGL(pool0_wconv_kernel, dim3(1280), dim3(256), 0, stream,
                       x, w, yT, wT);
    hipLaunchKernelGGL(gemm0_pool1_kernel, dim3(1536), dim3(256), 0, stream,
                       x, wT, yT, gate);
    hipLaunchKernelGGL(gemm1_apply0_kernel, dim3(1536), dim3(256), 0, stream,
                       x, wT, yT, gate, out);
    hipLaunchKernelGGL(apply1_kernel, dim3(1024), dim3(256), 0, stream,
                       x, gate, out);
}

// Round 18
// 412.197 us; speedup vs baseline: 1.0852x; 1.0198x over previous
//
#include <hip/hip_runtime.h>
#include <hip/hip_bf16.h>

// Problem constants
#define HH 256
#define WW 256
#define CCH 1024
#define PP 1024   // 32*32 patches per image

using f32x4 = __attribute__((ext_vector_type(4))) float;
using short8 = __attribute__((ext_vector_type(8))) short;

// ---------------------------------------------------------------------------
// pool_direct (R10-proven, byte-identical): job = ph*32 + cc -> patches
// (ph, 0..31) of planes cc*32..cc*32+31.  NT f32x4 slab reads, shfl_xor(1)
// pair-reduce -> LDS; writeback short8 (16B), 64B cross-block granularity.
// ---------------------------------------------------------------------------
__device__ __forceinline__ void pool_direct_body(const float* __restrict__ xb,
                                                 __hip_bfloat16* __restrict__ yTb,
                                                 int job, int t) {
    __shared__ float lds[32][33];
    int ph = job >> 5, c0 = (job & 31) * 32;
    int wid = t >> 6, lane = t & 63;
#pragma unroll 2
    for (int i = 0; i < 8; ++i) {
        int cl = wid * 8 + i;
        const float* base = xb + (size_t)(c0 + cl) * (HH * WW)
                          + (size_t)ph * 8 * WW + lane * 4;
        float acc = 0.f;
#pragma unroll
        for (int r = 0; r < 8; ++r) {
            f32x4 v = __builtin_nontemporal_load((const f32x4*)(base + r * WW));
            acc += v.x + v.y + v.z + v.w;
        }
        acc += __shfl_xor(acc, 1);
        if ((lane & 1) == 0)
            lds[lane >> 1][cl] = acc * (1.f / 64.f);
    }
    __syncthreads();
    if (t < 128) {
        int row = t >> 2, q = t & 3;
        short8 s;
#pragma unroll
        for (int j = 0; j < 8; ++j) {
            __hip_bfloat16 h = __float2bfloat16(lds[row][q * 8 + j]);
            s[j] = (short)reinterpret_cast<unsigned short&>(h);
        }
        *(short8*)(yTb + (size_t)(1 + ph * 32 + row) * CCH + c0 + q * 8) = s;
    }
}

// ---------------------------------------------------------------------------
// gemm body (R10-proven, byte-identical): block = 64(co) x 32(p), 4 waves
// along co, wave tile 16x32.  job in 0..511.
// ---------------------------------------------------------------------------
__device__ __forceinline__ void gemm_body(const __hip_bfloat16* __restrict__ wT,
                                          const __hip_bfloat16* __restrict__ yTb,
                                          float* __restrict__ gateb,
                                          int job, int tid) {
    int lane = tid & 63;
    int wid  = tid >> 6;
    int l15 = lane & 15, lhi = lane >> 4;
    int co_base = (job & 15) * 64 + wid * 16;
    int p_base  = (job >> 4) * 32;
    f32x4 acc[2] = {};
#pragma unroll
    for (int tap = 0; tap < 3; ++tap) {
        const __hip_bfloat16* Ap = wT + (size_t)tap * (1u << 20)
                                 + (size_t)(co_base + l15) * CCH + lhi * 8;
        const __hip_bfloat16* Bp = yTb + (size_t)(p_base + l15 + tap) * CCH + lhi * 8;
        for (int ci0 = 0; ci0 < CCH; ci0 += 32) {
            short8 a0 = *(const short8*)(Ap + ci0);
            short8 b0 = *(const short8*)(Bp + ci0);
            short8 b1 = *(const short8*)(Bp + ci0 + 16 * CCH);
            acc[0] = __builtin_amdgcn_mfma_f32_16x16x32_bf16(a0, b0, acc[0], 0, 0, 0);
            acc[1] = __builtin_amdgcn_mfma_f32_16x16x32_bf16(a0, b1, acc[1], 0, 0, 0);
        }
    }
    // C/D layout: col = lane&15, row = (lane>>4)*4 + reg  [m89/m91].
#pragma unroll
    for (int j16 = 0; j16 < 2; ++j16) {
        int col  = p_base + j16 * 16 + l15;
        int row0 = co_base + lhi * 4;
#pragma unroll
        for (int r = 0; r < 4; ++r)
            gateb[(size_t)(row0 + r) * PP + col] = 1.f / (1.f + __expf(-acc[j16][r]));
    }
}

// ---------------------------------------------------------------------------
// apply HALF-PLANE body (R18 change): job = plane*2 + half; block covers 128
// rows of one plane.  Gate slice (512 f32, 2KB) in LDS; NT loads + NT stores;
// unroll 8 for deeper MLP.  2048 blocks/batch = 8/CU -> halved tail quantum.
// ---------------------------------------------------------------------------
__device__ __forceinline__ void apply_body(const float* __restrict__ xb,
                                           const float* __restrict__ gateb,
                                           float* __restrict__ outb,
                                           int job, int t) {
    __shared__ __align__(16) float g[512];
    int c = job >> 1, half = job & 1;
    const float* xp = xb   + (size_t)c * (HH * WW) + (size_t)half * 128 * WW;
    float*       op = outb + (size_t)c * (HH * WW) + (size_t)half * 128 * WW;
    if (t < 128)
        ((f32x4*)g)[t] = ((const f32x4*)(gateb + (size_t)c * PP + half * 512))[t];
    __syncthreads();
    int col4 = t & 63;
    int r    = t >> 6;
    int pc   = col4 >> 1;
#pragma unroll 8
    for (int it = 0; it < 32; ++it) {
        int row = it * 4 + r;                    // 0..127 within half
        float gg = g[(row >> 3) * 32 + pc];
        size_t off = (size_t)row * 64 + col4;    // f32x4 units
        f32x4 v = __builtin_nontemporal_load((const f32x4*)xp + off);
        v *= gg;
        __builtin_nontemporal_store(v, (f32x4*)op + off);
    }
}

// ---------------------------------------------------------------------------
// L1: pool_direct(b0) [blocks 0..1023] ∥ wconv+pad [blocks 1024..1279].
// ---------------------------------------------------------------------------
__global__ __launch_bounds__(256) void pool0_wconv_kernel(
        const float* __restrict__ x, const float* __restrict__ w,
        __hip_bfloat16* __restrict__ yT, __hip_bfloat16* __restrict__ wT) {
    int bid = blockIdx.x, t = threadIdx.x;
    if (bid < 1024) {
        pool_direct_body(x, yT, bid, t);
    } else {
        int base = (bid - 1024) * 256 + t;       // 0..65535
#pragma unroll
        for (int it = 0; it < 16; ++it) {
            int idx = it * (1 << 16) + base;     // co*1024+ci
            const float* p = w + (size_t)idx * 3;
            wT[idx]               = __float2bfloat16(p[0]);
            wT[(1u << 20) + idx]  = __float2bfloat16(p[1]);
            wT[(2u << 20) + idx]  = __float2bfloat16(p[2]);
        }
        if (base < 2 * CCH) {
            int bb = base >> 10, cc = base & 1023;
            __hip_bfloat16 z = __float2bfloat16(0.f);
            __hip_bfloat16* basep = yT + (size_t)bb * (PP + 2) * CCH;
            basep[cc] = z;
            basep[(size_t)(PP + 1) * CCH + cc] = z;
        }
    }
}

// ---------------------------------------------------------------------------
// L2: gemm0 [blocks 0..511] ∥ pool_direct(b1) [512..1535].
// ---------------------------------------------------------------------------
__global__ __launch_bounds__(256) void gemm0_pool1_kernel(
        const float* __restrict__ x, const __hip_bfloat16* __restrict__ wT,
        __hip_bfloat16* __restrict__ yT, float* __restrict__ gate) {
    int bid = blockIdx.x, t = threadIdx.x;
    if (bid < 512) {
        gemm_body(wT, yT, gate, bid, t);
    } else {
        const float* x1 = x + (size_t)CCH * HH * WW;
        __hip_bfloat16* yT1 = yT + (size_t)(PP + 2) * CCH;
        pool_direct_body(x1, yT1, bid - 512, t);
    }
}

// ---------------------------------------------------------------------------
// L3: gemm1 [blocks 0..511] ∥ apply0 half-planes [512..2559, reversed].
// ---------------------------------------------------------------------------
__global__ __launch_bounds__(256) void gemm1_apply0_kernel(
        const float* __restrict__ x, const __hip_bfloat16* __restrict__ wT,
        const __hip_bfloat16* __restrict__ yT, float* __restrict__ gate,
        float* __restrict__ out) {
    int bid = blockIdx.x, t = threadIdx.x;
    if (bid < 512) {
        const __hip_bfloat16* yT1 = yT + (size_t)(PP + 2) * CCH;
        float* gate1 = gate + (size_t)CCH * PP;
        gemm_body(wT, yT1, gate1, bid, t);
    } else {
        apply_body(x, gate, out, 2047 - (bid - 512), t);
    }
}

// ---------------------------------------------------------------------------
// L4: apply1 half-planes (reversed).
// ---------------------------------------------------------------------------
__global__ __launch_bounds__(256) void apply1_kernel(
        const float* __restrict__ x, const float* __restrict__ gate,
        float* __restrict__ out) {
    const float* x1    = x    + (size_t)CCH * HH * WW;
    const float* gate1 = gate + (size_t)CCH * PP;
    float*       out1  = out  + (size_t)CCH * HH * WW;
    apply_body(x1, gate1, out1, 2047 - blockIdx.x, threadIdx.x);
}

extern "C" void kernel_launch(void* const* d_in, const int* in_sizes, int n_in,
                              void* d_out, int out_size, void* d_ws, size_t ws_size,
                              hipStream_t stream) {
    const float* x = (const float*)d_in[0];       // [2,1024,256,256] f32
    const float* w = (const float*)d_in[1];       // [1024,1024,3] f32
    float* out = (float*)d_out;                   // [2,1024,256,256] f32

    // Workspace layout (256-aligned):
    //   yT   bf16 [2][1026][1024]   4,202,496 B @ 0
    //   wT   bf16 [3][1024][1024]   6,291,456 B @  4,202,496
    //   gate f32  [2][1024][1024]   8,388,608 B @ 10,493,952   (tot ~18.9 MiB)
    char* ws = (char*)d_ws;
    __hip_bfloat16* yT   = (__hip_bfloat16*)(ws);
    __hip_bfloat16* wT   = (__hip_bfloat16*)(ws + 4202496);
    float*          gate = (float*)(ws + 10493952);

    hipLaunchKernelGGL(pool0_wconv_kernel, dim3(1280), dim3(256), 0, stream,
                       x, w, yT, wT);
    hipLaunchKernelGGL(gemm0_pool1_kernel, dim3(1536), dim3(256), 0, stream,
                       x, wT, yT, gate);
    hipLaunchKernelGGL(gemm1_apply0_kernel, dim3(2560), dim3(256), 0, stream,
                       x, wT, yT, gate, out);
    hipLaunchKernelGGL(apply1_kernel, dim3(2048), dim3(256), 0, stream,
                       x, gate, out);
}

// Round 19
// 404.468 us; speedup vs baseline: 1.1060x; 1.0191x over previous
//
#include <hip/hip_runtime.h>
#include <hip/hip_bf16.h>

// ============================================================================
// FINAL CONFIG (= R10, the measured optimum: 404 µs).
//
// Structure: 4 launches, range-split mixed grids; both GEMMs hidden under
// the two big HBM streams; all cross-block writes >=64B-granular (replay-
// safe under graph capture).
//
//   L1: pool_direct(b0)   ∥ wconv+pad
//   L2: gemm0             ∥ pool_direct(b1)
//   L3: gemm1             ∥ apply0 (reversed planes)
//   L4: apply1 (reversed planes)
//
// Roofline argument (measured, rounds 1-18):
//   - mandatory HBM traffic 1.64 GB (x read 2x: conv mixes all channels, so
//     the gate for any plane needs the pool of every plane; out written 1x)
//   - copy-ubench floor 256 us; our streams reach ~75-80% of copy ubench
//     (6 independent stream-shape rewrites all neutral-to-worse)
//   - 4 ordered launches minimum to hide both GEMMs; ~15 us/launch gap
//   -> composite 392-410 us; observed 404 us.
// ============================================================================

// Problem constants
#define HH 256
#define WW 256
#define CCH 1024
#define PP 1024   // 32*32 patches per image

using f32x4 = __attribute__((ext_vector_type(4))) float;
using short8 = __attribute__((ext_vector_type(8))) short;

// ---------------------------------------------------------------------------
// pool_direct: job = ph*32 + cc -> patches (ph, 0..31) of planes
// cc*32..cc*32+31.  NT f32x4 slab reads, shfl_xor(1) pair-reduce -> LDS;
// writeback short8 (16B), 64B cross-block granularity.
// ---------------------------------------------------------------------------
__device__ __forceinline__ void pool_direct_body(const float* __restrict__ xb,
                                                 __hip_bfloat16* __restrict__ yTb,
                                                 int job, int t) {
    __shared__ float lds[32][33];
    int ph = job >> 5, c0 = (job & 31) * 32;
    int wid = t >> 6, lane = t & 63;
#pragma unroll 2
    for (int i = 0; i < 8; ++i) {
        int cl = wid * 8 + i;
        const float* base = xb + (size_t)(c0 + cl) * (HH * WW)
                          + (size_t)ph * 8 * WW + lane * 4;
        float acc = 0.f;
#pragma unroll
        for (int r = 0; r < 8; ++r) {
            f32x4 v = __builtin_nontemporal_load((const f32x4*)(base + r * WW));
            acc += v.x + v.y + v.z + v.w;
        }
        acc += __shfl_xor(acc, 1);
        if ((lane & 1) == 0)
            lds[lane >> 1][cl] = acc * (1.f / 64.f);
    }
    __syncthreads();
    if (t < 128) {
        int row = t >> 2, q = t & 3;
        short8 s;
#pragma unroll
        for (int j = 0; j < 8; ++j) {
            __hip_bfloat16 h = __float2bfloat16(lds[row][q * 8 + j]);
            s[j] = (short)reinterpret_cast<unsigned short&>(h);
        }
        *(short8*)(yTb + (size_t)(1 + ph * 32 + row) * CCH + c0 + q * 8) = s;
    }
}

// ---------------------------------------------------------------------------
// gemm body: block = 64(co) x 32(p), 4 waves along co, wave tile 16x32.
// job in 0..511.  Operands L2/L3-resident; sigmoid fused in epilogue.
// ---------------------------------------------------------------------------
__device__ __forceinline__ void gemm_body(const __hip_bfloat16* __restrict__ wT,
                                          const __hip_bfloat16* __restrict__ yTb,
                                          float* __restrict__ gateb,
                                          int job, int tid) {
    int lane = tid & 63;
    int wid  = tid >> 6;
    int l15 = lane & 15, lhi = lane >> 4;
    int co_base = (job & 15) * 64 + wid * 16;
    int p_base  = (job >> 4) * 32;
    f32x4 acc[2] = {};
#pragma unroll
    for (int tap = 0; tap < 3; ++tap) {
        const __hip_bfloat16* Ap = wT + (size_t)tap * (1u << 20)
                                 + (size_t)(co_base + l15) * CCH + lhi * 8;
        const __hip_bfloat16* Bp = yTb + (size_t)(p_base + l15 + tap) * CCH + lhi * 8;
        for (int ci0 = 0; ci0 < CCH; ci0 += 32) {
            short8 a0 = *(const short8*)(Ap + ci0);
            short8 b0 = *(const short8*)(Bp + ci0);
            short8 b1 = *(const short8*)(Bp + ci0 + 16 * CCH);
            acc[0] = __builtin_amdgcn_mfma_f32_16x16x32_bf16(a0, b0, acc[0], 0, 0, 0);
            acc[1] = __builtin_amdgcn_mfma_f32_16x16x32_bf16(a0, b1, acc[1], 0, 0, 0);
        }
    }
    // C/D layout: col = lane&15, row = (lane>>4)*4 + reg  [m89/m91].
#pragma unroll
    for (int j16 = 0; j16 < 2; ++j16) {
        int col  = p_base + j16 * 16 + l15;
        int row0 = co_base + lhi * 4;
#pragma unroll
        for (int r = 0; r < 4; ++r)
            gateb[(size_t)(row0 + r) * PP + col] = 1.f / (1.f + __expf(-acc[j16][r]));
    }
}

// ---------------------------------------------------------------------------
// apply body: block per plane; gate row (4KB) in LDS (conflict-free 2-lane
// broadcast); wave covers a full 256-col row per iter.  NT loads + NT stores.
// ---------------------------------------------------------------------------
__device__ __forceinline__ void apply_body(const float* __restrict__ xb,
                                           const float* __restrict__ gateb,
                                           float* __restrict__ outb,
                                           int c, int t) {
    __shared__ __align__(16) float g[PP];
    const float* xp = xb   + (size_t)c * (HH * WW);
    float*       op = outb + (size_t)c * (HH * WW);
    ((f32x4*)g)[t] = ((const f32x4*)(gateb + (size_t)c * PP))[t];
    __syncthreads();
    int col4 = t & 63;
    int r    = t >> 6;
    int pc   = col4 >> 1;
#pragma unroll 4
    for (int it = 0; it < 64; ++it) {
        int row = it * 4 + r;
        float gg = g[(row >> 3) * 32 + pc];
        size_t off = (size_t)row * 64 + col4;
        f32x4 v = __builtin_nontemporal_load((const f32x4*)xp + off);
        v *= gg;
        __builtin_nontemporal_store(v, (f32x4*)op + off);
    }
}

// ---------------------------------------------------------------------------
// L1: pool_direct(b0) [blocks 0..1023] ∥ wconv+pad [blocks 1024..1279].
// ---------------------------------------------------------------------------
__global__ __launch_bounds__(256) void pool0_wconv_kernel(
        const float* __restrict__ x, const float* __restrict__ w,
        __hip_bfloat16* __restrict__ yT, __hip_bfloat16* __restrict__ wT) {
    int bid = blockIdx.x, t = threadIdx.x;
    if (bid < 1024) {
        pool_direct_body(x, yT, bid, t);
    } else {
        int base = (bid - 1024) * 256 + t;       // 0..65535
#pragma unroll
        for (int it = 0; it < 16; ++it) {
            int idx = it * (1 << 16) + base;     // co*1024+ci
            const float* p = w + (size_t)idx * 3;
            wT[idx]               = __float2bfloat16(p[0]);
            wT[(1u << 20) + idx]  = __float2bfloat16(p[1]);
            wT[(2u << 20) + idx]  = __float2bfloat16(p[2]);
        }
        if (base < 2 * CCH) {
            int bb = base >> 10, cc = base & 1023;
            __hip_bfloat16 z = __float2bfloat16(0.f);
            __hip_bfloat16* basep = yT + (size_t)bb * (PP + 2) * CCH;
            basep[cc] = z;
            basep[(size_t)(PP + 1) * CCH + cc] = z;
        }
    }
}

// ---------------------------------------------------------------------------
// L2: gemm0 [blocks 0..511] ∥ pool_direct(b1) [512..1535].
// ---------------------------------------------------------------------------
__global__ __launch_bounds__(256) void gemm0_pool1_kernel(
        const float* __restrict__ x, const __hip_bfloat16* __restrict__ wT,
        __hip_bfloat16* __restrict__ yT, float* __restrict__ gate) {
    int bid = blockIdx.x, t = threadIdx.x;
    if (bid < 512) {
        gemm_body(wT, yT, gate, bid, t);
    } else {
        const float* x1 = x + (size_t)CCH * HH * WW;
        __hip_bfloat16* yT1 = yT + (size_t)(PP + 2) * CCH;
        pool_direct_body(x1, yT1, bid - 512, t);
    }
}

// ---------------------------------------------------------------------------
// L3: gemm1 [blocks 0..511] ∥ apply0 [512..1535, reversed planes].
// ---------------------------------------------------------------------------
__global__ __launch_bounds__(256) void gemm1_apply0_kernel(
        const float* __restrict__ x, const __hip_bfloat16* __restrict__ wT,
        const __hip_bfloat16* __restrict__ yT, float* __restrict__ gate,
        float* __restrict__ out) {
    int bid = blockIdx.x, t = threadIdx.x;
    if (bid < 512) {
        const __hip_bfloat16* yT1 = yT + (size_t)(PP + 2) * CCH;
        float* gate1 = gate + (size_t)CCH * PP;
        gemm_body(wT, yT1, gate1, bid, t);
    } else {
        apply_body(x, gate, out, 1023 - (bid - 512), t);
    }
}

// ---------------------------------------------------------------------------
// L4: apply1 (reversed planes).
// ---------------------------------------------------------------------------
__global__ __launch_bounds__(256) void apply1_kernel(
        const float* __restrict__ x, const float* __restrict__ gate,
        float* __restrict__ out) {
    const float* x1    = x    + (size_t)CCH * HH * WW;
    const float* gate1 = gate + (size_t)CCH * PP;
    float*       out1  = out  + (size_t)CCH * HH * WW;
    apply_body(x1, gate1, out1, 1023 - blockIdx.x, threadIdx.x);
}

extern "C" void kernel_launch(void* const* d_in, const int* in_sizes, int n_in,
                              void* d_out, int out_size, void* d_ws, size_t ws_size,
                              hipStream_t stream) {
    const float* x = (const float*)d_in[0];       // [2,1024,256,256] f32
    const float* w = (const float*)d_in[1];       // [1024,1024,3] f32
    float* out = (float*)d_out;                   // [2,1024,256,256] f32

    // Workspace layout (256-aligned):
    //   yT   bf16 [2][1026][1024]   4,202,496 B @ 0
    //   wT   bf16 [3][1024][1024]   6,291,456 B @  4,202,496
    //   gate f32  [2][1024][1024]   8,388,608 B @ 10,493,952   (tot ~18.9 MiB)
    char* ws = (char*)d_ws;
    __hip_bfloat16* yT   = (__hip_bfloat16*)(ws);
    __hip_bfloat16* wT   = (__hip_bfloat16*)(ws + 4202496);
    float*          gate = (float*)(ws + 10493952);

    hipLaunchKernelGGL(pool0_wconv_kernel, dim3(1280), dim3(256), 0, stream,
                       x, w, yT, wT);
    hipLaunchKernelGGL(gemm0_pool1_kernel, dim3(1536), dim3(256), 0, stream,
                       x, wT, yT, gate);
    hipLaunchKernelGGL(gemm1_apply0_kernel, dim3(1536), dim3(256), 0, stream,
                       x, wT, yT, gate, out);
    hipLaunchKernelGGL(apply1_kernel, dim3(1024), dim3(256), 0, stream,
                       x, gate, out);
}